// Round 10
// baseline (329.530 us; speedup 1.0000x reference)
//
#include <hip/hip_runtime.h>

typedef unsigned short ushort;
typedef __attribute__((ext_vector_type(8))) short short8;
typedef __attribute__((ext_vector_type(4))) float f32x4;

#define NH 16
#define DH 128
#define SEQ 2048
#define DMODEL 2048
#define GK 2048   // K dim for both GEMMs
#define NT 32     // GK / 64

#define WAITVM(N) asm volatile("s_waitcnt vmcnt(" #N ")" ::: "memory")

__device__ __forceinline__ ushort f2bf(float f) {
  union { float f; unsigned u; } v; v.f = f;
  unsigned u = v.u;
  unsigned r = (u + 0x7fffu + ((u >> 16) & 1u)) >> 16;
  return (ushort)r;
}
__device__ __forceinline__ float bf2f(ushort h) {
  union { unsigned u; float f; } v; v.u = ((unsigned)h) << 16; return v.f;
}

__device__ __forceinline__ void async16(const ushort* g, ushort* l) {
  __builtin_amdgcn_global_load_lds(
      (const __attribute__((address_space(1))) unsigned*)g,
      (__attribute__((address_space(3))) unsigned*)l, 16, 0, 0);
}

// ---------------- cast fp32 -> bf16, 4 elems/thread ----------------
__global__ void cast_kernel(const float* __restrict__ src, ushort* __restrict__ dst, int n4) {
  int i = blockIdx.x * blockDim.x + threadIdx.x;
  if (i >= n4) return;
  float4 v = ((const float4*)src)[i];
  unsigned long long p = (unsigned long long)f2bf(v.x)
                       | ((unsigned long long)f2bf(v.y) << 16)
                       | ((unsigned long long)f2bf(v.z) << 32)
                       | ((unsigned long long)f2bf(v.w) << 48);
  ((unsigned long long*)dst)[i] = p;
}

// ---------------- 256x256 GEMM, m201 wave geometry ----------------
// C = A[M,K] * B[N,K]^T.  512 threads = 8 waves (2M x 4N); WAVE TILE 128x64
// (Mf=8, Nf=4 -> 0.375 KB LDS-read per MFMA; LDS-BW ceiling ~62% vs 31% for
// 64x64 waves -- the r7-r9 limiter).  BK=64, double-buffered (128 KB LDS),
// XOR-swizzled (pre-swizzled global source + swizzled ds_read; 0 conflicts).
// Per tile: [bar][stage t+1: 8 loads][vmcnt(8) -- waits loads issued 1 full
// tile ago][bar][hoist B frags][4 phases: 4 A-reads + 16 MFMA].
// Races: stage->buf[(t+1)&1], last read at tile t-1, separated by top barrier;
// post-wait barrier collectivizes per-wave vmcnt.  XCD-swizzled block order.
__device__ __forceinline__ void stage256(const ushort* blk, int k0, ushort* dst, int tid) {
#pragma unroll
  for (int j = 0; j < 4; ++j) {
    int c = j * 512 + tid;                 // 2048 chunks of 16B (256 rows x 64)
    int row = c >> 3, sl = c & 7;
    int col = ((sl * 16) ^ ((row & 7) << 4)) >> 1;
    async16(blk + (size_t)row * GK + k0 + col, dst + c * 8);
  }
}

template<int MODE>
__global__ __launch_bounds__(512, 1)
void gemm256(const ushort* __restrict__ A, const ushort* __restrict__ B, int N,
             ushort* __restrict__ oq, ushort* __restrict__ ok, ushort* __restrict__ ov,
             float* __restrict__ of) {
  __shared__ ushort As[2][256 * 64];       // 64 KB
  __shared__ ushort Bs[2][256 * 64];       // 64 KB
  const int tid = threadIdx.x;
  const int lane = tid & 63;
  const int w = tid >> 6;
  const int wm = w >> 2, wn = w & 3;       // 2 x 4 waves; wave tile 128x64
  const int g = lane >> 4, l16 = lane & 15;

  // bijective XCD swizzle (nwg % 8 == 0 for both grids: 384, 128)
  const int nwg = (int)(gridDim.x * gridDim.y);
  const int bid = (int)(blockIdx.y * gridDim.x + blockIdx.x);
  const int swz = (bid & 7) * (nwg >> 3) + (bid >> 3);
  const int m0 = (swz / (int)gridDim.x) * 256;
  const int n0 = (swz % (int)gridDim.x) * 256;
  const ushort* Ablk = A + (size_t)m0 * GK;
  const ushort* Bblk = B + (size_t)n0 * GK;

  f32x4 acc[8][4];
#pragma unroll
  for (int mf = 0; mf < 8; ++mf)
#pragma unroll
    for (int nf = 0; nf < 4; ++nf) acc[mf][nf] = (f32x4)0.f;

  // prologue: stage tile 0 into buffer 0
  stage256(Ablk, 0, (ushort*)As[0], tid);
  stage256(Bblk, 0, (ushort*)Bs[0], tid);

  for (int t = 0; t < NT; ++t) {
    const ushort* cA = As[t & 1];
    const ushort* cB = Bs[t & 1];
    ushort* nA = (ushort*)As[(t + 1) & 1];
    ushort* nB = (ushort*)Bs[(t + 1) & 1];

    __builtin_amdgcn_s_barrier();          // buf[(t+1)&1] readers (tile t-1) done
    if (t + 1 < NT) {
      stage256(Ablk, (t + 1) * 64, nA, tid);
      stage256(Bblk, (t + 1) * 64, nB, tid);
      WAITVM(8);                           // tile t's loads (1 full tile old)
    } else {
      WAITVM(0);                           // also 1 tile old -- harmless drain
    }
    __builtin_amdgcn_sched_barrier(0);
    __builtin_amdgcn_s_barrier();          // collectivize the vmcnt wait
    __builtin_amdgcn_sched_barrier(0);

    // hoist B fragments for the whole K-tile (8 x ds_read_b128, 32 VGPR)
    short8 bfr[4][2];
#pragma unroll
    for (int nf = 0; nf < 4; ++nf) {
      int row = wn * 64 + nf * 16 + l16;
#pragma unroll
      for (int ks = 0; ks < 2; ++ks)
        bfr[nf][ks] = *(const short8*)&cB[row * 64 + (((ks * 64 + g * 16) ^ ((l16 & 7) << 4)) >> 1)];
    }

    // 4 phases: phase p computes mf {2p, 2p+1} x 4 nf x 2 ks = 16 MFMA
#pragma unroll
    for (int p = 0; p < 4; ++p) {
      short8 af[2][2];
#pragma unroll
      for (int mi = 0; mi < 2; ++mi) {
        int row = wm * 128 + (2 * p + mi) * 16 + l16;
#pragma unroll
        for (int ks = 0; ks < 2; ++ks)
          af[mi][ks] = *(const short8*)&cA[row * 64 + (((ks * 64 + g * 16) ^ ((l16 & 7) << 4)) >> 1)];
      }
      __builtin_amdgcn_s_setprio(1);
#pragma unroll
      for (int mi = 0; mi < 2; ++mi)
#pragma unroll
        for (int nf = 0; nf < 4; ++nf)
#pragma unroll
          for (int ks = 0; ks < 2; ++ks)
            acc[2 * p + mi][nf] = __builtin_amdgcn_mfma_f32_16x16x32_bf16(
                af[mi][ks], bfr[nf][ks], acc[2 * p + mi][nf], 0, 0, 0);
      __builtin_amdgcn_s_setprio(0);
    }
  }

#pragma unroll
  for (int mf = 0; mf < 8; ++mf)
#pragma unroll
    for (int nf = 0; nf < 4; ++nf)
#pragma unroll
      for (int i = 0; i < 4; ++i) {
        int row = m0 + wm * 128 + mf * 16 + g * 4 + i;
        int col = n0 + wn * 64 + nf * 16 + l16;
        float val = acc[mf][nf][i];
        if (MODE == 0) {
          int which = col >> 11;
          int r = col & 2047;
          int h = r >> 7, dh = r & 127;
          int b = row >> 11, s = row & 2047;
          size_t dst = ((size_t)(b * NH + h) * SEQ + s) * DH + dh;
          ushort* o = (which == 0) ? oq : (which == 1 ? ok : ov);
          o[dst] = f2bf(val);
        } else {
          of[(size_t)row * N + col] = val;
        }
      }
}

// ---------------- RoPE (in-place on head-major bf16 q,k) ----------------
__global__ void rope_kernel(ushort* __restrict__ q, ushort* __restrict__ k,
                            const int* __restrict__ spp) {
  int id = blockIdx.x * blockDim.x + threadIdx.x;   // < B*H*S*64
  int j = id & 63;
  int s = (id >> 6) & (SEQ - 1);
  int bh = id >> 17;
  size_t base = ((size_t)bh * SEQ + s) * DH;
  float pos = (float)(s + spp[0]);
  float ang = pos * __expf(-(float)j * (9.210340371976184f / 64.f)); // 1/10000^(j/64)
  float c = cosf(ang), sn = sinf(ang);
  float q1 = bf2f(q[base + j]), q2 = bf2f(q[base + 64 + j]);
  q[base + j]      = f2bf(q1 * c - q2 * sn);
  q[base + 64 + j] = f2bf(q2 * c + q1 * sn);
  float k1 = bf2f(k[base + j]), k2 = bf2f(k[base + 64 + j]);
  k[base + j]      = f2bf(k1 * c - k2 * sn);
  k[base + 64 + j] = f2bf(k2 * c + k1 * sn);
}

// ---------------- causal flash attention (unchanged, passing) ----------------
__global__ __launch_bounds__(256, 2)
void attn_kernel(const ushort* __restrict__ Q, const ushort* __restrict__ K,
                 const ushort* __restrict__ V, ushort* __restrict__ O) {
  __shared__ ushort Ks[2][64 * 128];     // 32 KB
  __shared__ ushort Vt[2][128 * 72];     // 36 KB
  __shared__ ushort Ps[4][16 * 72];      // 9 KB
  const int tid = threadIdx.x;
  const int lane = tid & 63;
  const int w = tid >> 6;
  const int g = lane >> 4, l16 = lane & 15;
  const int h = blockIdx.y, b = blockIdx.z;
  const int bh = b * NH + h;
  const ushort* Qb = Q + (size_t)bh * SEQ * DH;
  const ushort* Kb = K + (size_t)bh * SEQ * DH;
  const ushort* Vb = V + (size_t)bh * SEQ * DH;
  const float scale = 0.08838834764831845f;  // 1/sqrt(128)

  const int vkv = (tid >> 3) * 2;       // 0..62
  const int vd0 = (tid & 7) * 16;       // 0..112
  const int vmask = (tid & 7) << 3;     // XOR swizzle ((d>>4)&7)<<3

  for (int pass = 0; pass < 2; ++pass) {
    const int qt = pass == 0 ? (31 - (int)blockIdx.x) : (int)blockIdx.x;
    const int q0 = qt * 64;
    const int nkt = qt + 1;

    short8 qf[4];
    {
      const ushort* qrow = Qb + (size_t)(q0 + w * 16 + l16) * DH;
#pragma unroll
      for (int ks = 0; ks < 4; ++ks) qf[ks] = *(const short8*)(qrow + ks * 32 + g * 8);
    }
    f32x4 oacc[8];
#pragma unroll
    for (int i = 0; i < 8; ++i) oacc[i] = (f32x4)0.f;
    float m_i[4], l_i[4];
#pragma unroll
    for (int i = 0; i < 4; ++i) { m_i[i] = -INFINITY; l_i[i] = 0.f; }

#pragma unroll
    for (int it = 0; it < 4; ++it) {
      int ci = it * 256 + tid;
      int row = ci >> 4;
      int cb = ((ci & 15) * 16) ^ ((row & 7) << 4);
      async16(Kb + (size_t)row * DH + (cb >> 1), &Ks[0][ci * 8]);
    }
    {
      short8 vr[4];
      vr[0] = *(const short8*)(Vb + (size_t)vkv * DH + vd0);
      vr[1] = *(const short8*)(Vb + (size_t)vkv * DH + vd0 + 8);
      vr[2] = *(const short8*)(Vb + (size_t)(vkv + 1) * DH + vd0);
      vr[3] = *(const short8*)(Vb + (size_t)(vkv + 1) * DH + vd0 + 8);
#pragma unroll
      for (int j = 0; j < 16; ++j) {
        int d = vd0 + j;
        const ushort* a = (const ushort*)&vr[j >> 3];
        const ushort* c = (const ushort*)&vr[2 + (j >> 3)];
        unsigned val = (unsigned)a[j & 7] | ((unsigned)c[j & 7] << 16);
        *(unsigned*)&Vt[0][d * 72 + (vkv ^ vmask)] = val;
      }
    }
    __syncthreads();

    int cur = 0;
    for (int t = 0; t < nkt; ++t) {
      const int k0 = t * 64;
      const int nxt = cur ^ 1;
      const bool pre = (t + 1 < nkt);
      short8 vr[4];
      if (pre) {
        const int kn = (t + 1) * 64;
#pragma unroll
        for (int it = 0; it < 4; ++it) {
          int ci = it * 256 + tid;
          int row = ci >> 4;
          int cb = ((ci & 15) * 16) ^ ((row & 7) << 4);
          async16(Kb + (size_t)(kn + row) * DH + (cb >> 1), &Ks[nxt][ci * 8]);
        }
        vr[0] = *(const short8*)(Vb + (size_t)(kn + vkv) * DH + vd0);
        vr[1] = *(const short8*)(Vb + (size_t)(kn + vkv) * DH + vd0 + 8);
        vr[2] = *(const short8*)(Vb + (size_t)(kn + vkv + 1) * DH + vd0);
        vr[3] = *(const short8*)(Vb + (size_t)(kn + vkv + 1) * DH + vd0 + 8);
      }

      f32x4 sacc[4];
#pragma unroll
      for (int nf = 0; nf < 4; ++nf) sacc[nf] = (f32x4)0.f;
      __builtin_amdgcn_s_setprio(1);
#pragma unroll
      for (int nf = 0; nf < 4; ++nf) {
        int row = nf * 16 + l16;
#pragma unroll
        for (int ks = 0; ks < 4; ++ks) {
          int cb = (ks * 64 + g * 16) ^ ((l16 & 7) << 4);
          short8 kf = *(const short8*)&Ks[cur][row * 128 + (cb >> 1)];
          sacc[nf] = __builtin_amdgcn_mfma_f32_16x16x32_bf16(qf[ks], kf, sacc[nf], 0, 0, 0);
        }
      }
      __builtin_amdgcn_s_setprio(0);

#pragma unroll
      for (int i = 0; i < 4; ++i) {
        int qrow = q0 + w * 16 + g * 4 + i;
        float pv[4];
#pragma unroll
        for (int nf = 0; nf < 4; ++nf) {
          pv[nf] = sacc[nf][i] * scale;
          if (k0 + nf * 16 + l16 > qrow) pv[nf] = -INFINITY;
        }
        float mx = fmaxf(fmaxf(pv[0], pv[1]), fmaxf(pv[2], pv[3]));
#pragma unroll
        for (int d = 1; d < 16; d <<= 1) mx = fmaxf(mx, __shfl_xor(mx, d, 64));
        float mnew = fmaxf(m_i[i], mx);
        float alpha = __expf(m_i[i] - mnew);
        float p[4], sum = 0.f;
#pragma unroll
        for (int nf = 0; nf < 4; ++nf) { p[nf] = __expf(pv[nf] - mnew); sum += p[nf]; }
#pragma unroll
        for (int d = 1; d < 16; d <<= 1) sum += __shfl_xor(sum, d, 64);
        l_i[i] = l_i[i] * alpha + sum;
        m_i[i] = mnew;
#pragma unroll
        for (int nf2 = 0; nf2 < 8; ++nf2) oacc[nf2][i] *= alpha;
#pragma unroll
        for (int nf = 0; nf < 4; ++nf)
          Ps[w][(g * 4 + i) * 72 + nf * 16 + l16] = f2bf(p[nf]);
      }
      __asm__ volatile("s_waitcnt lgkmcnt(0)" ::: "memory");
      __builtin_amdgcn_sched_barrier(0);

      __builtin_amdgcn_s_setprio(1);
#pragma unroll
      for (int kvh = 0; kvh < 2; ++kvh) {
        short8 pa = *(const short8*)&Ps[w][l16 * 72 + kvh * 32 + g * 8];
#pragma unroll
        for (int nf2 = 0; nf2 < 8; ++nf2) {
          int cb = (kvh * 32 + g * 8) ^ (nf2 * 8);
          short8 vf = *(const short8*)&Vt[cur][(nf2 * 16 + l16) * 72 + cb];
          oacc[nf2] = __builtin_amdgcn_mfma_f32_16x16x32_bf16(pa, vf, oacc[nf2], 0, 0, 0);
        }
      }
      __builtin_amdgcn_s_setprio(0);

      if (pre) {
#pragma unroll
        for (int j = 0; j < 16; ++j) {
          int d = vd0 + j;
          const ushort* a = (const ushort*)&vr[j >> 3];
          const ushort* c = (const ushort*)&vr[2 + (j >> 3)];
          unsigned val = (unsigned)a[j & 7] | ((unsigned)c[j & 7] << 16);
          *(unsigned*)&Vt[nxt][d * 72 + (vkv ^ vmask)] = val;
        }
      }
      __syncthreads();
      cur = nxt;
    }

#pragma unroll
    for (int i = 0; i < 4; ++i) {
      float inv = 1.f / l_i[i];
      int row = q0 + w * 16 + g * 4 + i;
      size_t obase = ((size_t)b * SEQ + row) * DMODEL + h * DH;
#pragma unroll
      for (int nf2 = 0; nf2 < 8; ++nf2)
        O[obase + nf2 * 16 + l16] = f2bf(oacc[nf2][i] * inv);
    }
  }
}

// ---------------- launch ----------------
extern "C" void kernel_launch(void* const* d_in, const int* in_sizes, int n_in,
                              void* d_out, int out_size, void* d_ws, size_t ws_size,
                              hipStream_t stream) {
  const float* x    = (const float*)d_in[0];
  const float* wqkv = (const float*)d_in[1];
  const float* wout = (const float*)d_in[2];
  const int*   spp  = (const int*)d_in[3];
  float* out = (float*)d_out;

  ushort* ws = (ushort*)d_ws;
  ushort* xb  = ws;                       // 8,388,608
  ushort* wqb = xb + 8388608;             // 12,582,912
  ushort* wob = wqb + 12582912;           // 4,194,304
  ushort* q   = wob + 4194304;            // 8,388,608
  ushort* k   = q + 8388608;
  ushort* v   = k + 8388608;
  ushort* ao  = v + 8388608;              // 8,388,608

  cast_kernel<<<8388608 / 1024, 256, 0, stream>>>(x, xb, 8388608 / 4);
  cast_kernel<<<12582912 / 1024, 256, 0, stream>>>(wqkv, wqb, 12582912 / 4);
  cast_kernel<<<4194304 / 1024, 256, 0, stream>>>(wout, wob, 4194304 / 4);

  gemm256<0><<<dim3(6144 / 256, 4096 / 256), 512, 0, stream>>>(xb, wqb, 6144, q, k, v, nullptr);

  rope_kernel<<<4194304 / 256, 256, 0, stream>>>(q, k, spp);

  attn_kernel<<<dim3(16, NH, 2), 256, 0, stream>>>(q, k, v, ao);

  gemm256<1><<<dim3(2048 / 256, 4096 / 256), 512, 0, stream>>>(ao, wob, 2048, nullptr, nullptr, nullptr, out);
}

// Round 11
// 310.033 us; speedup vs baseline: 1.0629x; 1.0629x over previous
//
#include <hip/hip_runtime.h>

typedef unsigned short ushort;
typedef __attribute__((ext_vector_type(8))) short short8;
typedef __attribute__((ext_vector_type(4))) float f32x4;

#define NH 16
#define DH 128
#define SEQ 2048
#define DMODEL 2048
#define GK 2048   // K dim for both GEMMs
#define NT 32     // GK / 64
#define NI 16     // NT / 2 (iterations of 2 K-tiles)

#define WAITVM(N) asm volatile("s_waitcnt vmcnt(" #N ")" ::: "memory")

__device__ __forceinline__ ushort f2bf(float f) {
  union { float f; unsigned u; } v; v.f = f;
  unsigned u = v.u;
  unsigned r = (u + 0x7fffu + ((u >> 16) & 1u)) >> 16;
  return (ushort)r;
}
__device__ __forceinline__ float bf2f(ushort h) {
  union { unsigned u; float f; } v; v.u = ((unsigned)h) << 16; return v.f;
}

__device__ __forceinline__ void async16(const ushort* g, ushort* l) {
  __builtin_amdgcn_global_load_lds(
      (const __attribute__((address_space(1))) unsigned*)g,
      (__attribute__((address_space(3))) unsigned*)l, 16, 0, 0);
}

// ---------------- cast fp32 -> bf16, 4 elems/thread ----------------
__global__ void cast_kernel(const float* __restrict__ src, ushort* __restrict__ dst, int n4) {
  int i = blockIdx.x * blockDim.x + threadIdx.x;
  if (i >= n4) return;
  float4 v = ((const float4*)src)[i];
  unsigned long long p = (unsigned long long)f2bf(v.x)
                       | ((unsigned long long)f2bf(v.y) << 16)
                       | ((unsigned long long)f2bf(v.z) << 32)
                       | ((unsigned long long)f2bf(v.w) << 48);
  ((unsigned long long*)dst)[i] = p;
}

// ---------------- 256x256 GEMM, m201-style 8-phase schedule ----------------
// C = A[M,K] * B[N,K]^T.  512 threads = 8 waves (2M x 4N), wave tile 128x64.
// BK=64, 2 K-tiles per iteration (slot = t&1), 8 phases/iter.
// Phase p: [ds_read quadrant frags][stage ONE 128-row half (2 loads)]
//          [bar][MFMA 16 (setprio)][bar].
// Stage calendar (iter I; T0=2I,T1=2I+1,T2=2I+2,T3=2I+3):
//   p0,p1: A(T1)h0,h1 -> slot1   (slot1 A dead since prev-iter p7)
//   p2,p3: B(T2)h0,h1 -> slot0   (slot0 B dead after p0)
//   p4,p5: A(T2)h0,h1 -> slot0   (slot0 A dead after p3)
//   p6,p7: B(T3)h0,h1 -> slot1   (slot1 B dead after p4)
// Reads: q0 needs slot B (all) + A chunk0; q1-3 need A chunk q.
// Counted waits: vmcnt(4) at END of p3 (validates through p1 -> p4-7 reads)
// and END of p7 (validates through p5 -> next-iter p0-3 reads); the following
// s_barrier collectivizes.  Ledger verified incl. prologue (6 units) + tail.
__device__ __forceinline__ void stageHalf(const ushort* blk, int k0, int half,
                                          ushort* slotbuf, int tid) {
#pragma unroll
  for (int j = 0; j < 2; ++j) {
    int c = j * 512 + tid;                 // 1024 chunks of 16B per half
    int row = half * 128 + (c >> 3);
    int sl = c & 7;
    int col = ((sl * 16) ^ ((row & 7) << 4)) >> 1;   // pre-swizzled source
    async16(blk + (size_t)row * GK + k0 + col, slotbuf + row * 64 + sl * 8);
  }
}

template<int MODE>
__global__ __launch_bounds__(512, 1)
void gemm256(const ushort* __restrict__ A, const ushort* __restrict__ B, int N,
             ushort* __restrict__ oq, ushort* __restrict__ ok, ushort* __restrict__ ov,
             float* __restrict__ of) {
  __shared__ ushort As[2][256 * 64];       // 64 KB (slot per K-tile parity)
  __shared__ ushort Bs[2][256 * 64];       // 64 KB
  const int tid = threadIdx.x;
  const int lane = tid & 63;
  const int w = tid >> 6;
  const int wm = w >> 2, wn = w & 3;       // wave tile 128(M) x 64(N)
  const int g = lane >> 4, l16 = lane & 15;
  const int m0 = blockIdx.y * 256;
  const int n0 = blockIdx.x * 256;
  const ushort* Ablk = A + (size_t)m0 * GK;
  const ushort* Bblk = B + (size_t)n0 * GK;

  f32x4 acc[8][4];
#pragma unroll
  for (int mf = 0; mf < 8; ++mf)
#pragma unroll
    for (int nf = 0; nf < 4; ++nf) acc[mf][nf] = (f32x4)0.f;

  // prologue: A(T0), B(T0) -> slot0; B(T1) -> slot1   (12 loads/thread)
  stageHalf(Ablk, 0, 0, (ushort*)As[0], tid);
  stageHalf(Ablk, 0, 1, (ushort*)As[0], tid);
  stageHalf(Bblk, 0, 0, (ushort*)Bs[0], tid);
  stageHalf(Bblk, 0, 1, (ushort*)Bs[0], tid);
  stageHalf(Bblk, 64, 0, (ushort*)Bs[1], tid);
  stageHalf(Bblk, 64, 1, (ushort*)Bs[1], tid);
  WAITVM(8);                               // T0's A+B (8 oldest) landed
  __builtin_amdgcn_sched_barrier(0);
  __builtin_amdgcn_s_barrier();
  __builtin_amdgcn_sched_barrier(0);

  short8 bfr[4][2];
  for (int I = 0; I < NI; ++I) {
    const int T1 = 2 * I + 1, T2 = 2 * I + 2, T3 = 2 * I + 3;
#pragma unroll
    for (int p = 0; p < 8; ++p) {
      const int half = p >> 2;             // 0: slot0 (T0), 1: slot1 (T1)
      const int q = p & 3;
      const ushort* cA = As[half];
      const ushort* cB = Bs[half];

      // ---- ds_reads for this phase (validated by the previous barrier) ----
      if (q == 0) {
#pragma unroll
        for (int nf = 0; nf < 4; ++nf) {
          int row = wn * 64 + nf * 16 + l16;
#pragma unroll
          for (int ks = 0; ks < 2; ++ks)
            bfr[nf][ks] = *(const short8*)&cB[row * 64 + (((ks * 64 + g * 16) ^ ((l16 & 7) << 4)) >> 1)];
        }
      }
      short8 af[2][2];
#pragma unroll
      for (int mi = 0; mi < 2; ++mi) {
        int row = wm * 128 + (2 * q + mi) * 16 + l16;
#pragma unroll
        for (int ks = 0; ks < 2; ++ks)
          af[mi][ks] = *(const short8*)&cA[row * 64 + (((ks * 64 + g * 16) ^ ((l16 & 7) << 4)) >> 1)];
      }

      // ---- stage calendar (one half-unit = 2 loads) ----
      if (p == 0)                  stageHalf(Ablk, T1 * 64, 0, (ushort*)As[1], tid);
      else if (p == 1)             stageHalf(Ablk, T1 * 64, 1, (ushort*)As[1], tid);
      else if (p == 2) { if (T2 < NT) stageHalf(Bblk, T2 * 64, 0, (ushort*)Bs[0], tid); }
      else if (p == 3) { if (T2 < NT) stageHalf(Bblk, T2 * 64, 1, (ushort*)Bs[0], tid); }
      else if (p == 4) { if (T2 < NT) stageHalf(Ablk, T2 * 64, 0, (ushort*)As[0], tid); }
      else if (p == 5) { if (T2 < NT) stageHalf(Ablk, T2 * 64, 1, (ushort*)As[0], tid); }
      else if (p == 6) { if (T3 < NT) stageHalf(Bblk, T3 * 64, 0, (ushort*)Bs[1], tid); }
      else             { if (T3 < NT) stageHalf(Bblk, T3 * 64, 1, (ushort*)Bs[1], tid); }

      // ---- counted waits before the half-iteration boundary barriers ----
      if (p == 3) { if (T2 < NT) { WAITVM(4); } else { WAITVM(0); } }
      if (p == 7) { if (T3 < NT) { WAITVM(4); } else { WAITVM(0); } }

      __builtin_amdgcn_sched_barrier(0);
      __builtin_amdgcn_s_barrier();
      __builtin_amdgcn_sched_barrier(0);

      // ---- 16 MFMA: quadrant mf = {2q, 2q+1} x 4 nf x 2 ks ----
      __builtin_amdgcn_s_setprio(1);
#pragma unroll
      for (int mi = 0; mi < 2; ++mi)
#pragma unroll
        for (int nf = 0; nf < 4; ++nf)
#pragma unroll
          for (int ks = 0; ks < 2; ++ks)
            acc[2 * q + mi][nf] = __builtin_amdgcn_mfma_f32_16x16x32_bf16(
                af[mi][ks], bfr[nf][ks], acc[2 * q + mi][nf], 0, 0, 0);
      __builtin_amdgcn_s_setprio(0);

      __builtin_amdgcn_sched_barrier(0);
      __builtin_amdgcn_s_barrier();
      __builtin_amdgcn_sched_barrier(0);
    }
  }

#pragma unroll
  for (int mf = 0; mf < 8; ++mf)
#pragma unroll
    for (int nf = 0; nf < 4; ++nf)
#pragma unroll
      for (int i = 0; i < 4; ++i) {
        int row = m0 + wm * 128 + mf * 16 + g * 4 + i;
        int col = n0 + wn * 64 + nf * 16 + l16;
        float val = acc[mf][nf][i];
        if (MODE == 0) {
          int which = col >> 11;
          int r = col & 2047;
          int h = r >> 7, dh = r & 127;
          int b = row >> 11, s = row & 2047;
          size_t dst = ((size_t)(b * NH + h) * SEQ + s) * DH + dh;
          ushort* o = (which == 0) ? oq : (which == 1 ? ok : ov);
          o[dst] = f2bf(val);
        } else {
          of[(size_t)row * N + col] = val;
        }
      }
}

// ---------------- RoPE (in-place on head-major bf16 q,k) ----------------
__global__ void rope_kernel(ushort* __restrict__ q, ushort* __restrict__ k,
                            const int* __restrict__ spp) {
  int id = blockIdx.x * blockDim.x + threadIdx.x;   // < B*H*S*64
  int j = id & 63;
  int s = (id >> 6) & (SEQ - 1);
  int bh = id >> 17;
  size_t base = ((size_t)bh * SEQ + s) * DH;
  float pos = (float)(s + spp[0]);
  float ang = pos * __expf(-(float)j * (9.210340371976184f / 64.f)); // 1/10000^(j/64)
  float c = cosf(ang), sn = sinf(ang);
  float q1 = bf2f(q[base + j]), q2 = bf2f(q[base + 64 + j]);
  q[base + j]      = f2bf(q1 * c - q2 * sn);
  q[base + 64 + j] = f2bf(q2 * c + q1 * sn);
  float k1 = bf2f(k[base + j]), k2 = bf2f(k[base + 64 + j]);
  k[base + j]      = f2bf(k1 * c - k2 * sn);
  k[base + 64 + j] = f2bf(k2 * c + k1 * sn);
}

// ---------------- causal flash attention (unchanged, passing) ----------------
__global__ __launch_bounds__(256, 2)
void attn_kernel(const ushort* __restrict__ Q, const ushort* __restrict__ K,
                 const ushort* __restrict__ V, ushort* __restrict__ O) {
  __shared__ ushort Ks[2][64 * 128];     // 32 KB
  __shared__ ushort Vt[2][128 * 72];     // 36 KB
  __shared__ ushort Ps[4][16 * 72];      // 9 KB
  const int tid = threadIdx.x;
  const int lane = tid & 63;
  const int w = tid >> 6;
  const int g = lane >> 4, l16 = lane & 15;
  const int h = blockIdx.y, b = blockIdx.z;
  const int bh = b * NH + h;
  const ushort* Qb = Q + (size_t)bh * SEQ * DH;
  const ushort* Kb = K + (size_t)bh * SEQ * DH;
  const ushort* Vb = V + (size_t)bh * SEQ * DH;
  const float scale = 0.08838834764831845f;  // 1/sqrt(128)

  const int vkv = (tid >> 3) * 2;       // 0..62
  const int vd0 = (tid & 7) * 16;       // 0..112
  const int vmask = (tid & 7) << 3;     // XOR swizzle ((d>>4)&7)<<3

  for (int pass = 0; pass < 2; ++pass) {
    const int qt = pass == 0 ? (31 - (int)blockIdx.x) : (int)blockIdx.x;
    const int q0 = qt * 64;
    const int nkt = qt + 1;

    short8 qf[4];
    {
      const ushort* qrow = Qb + (size_t)(q0 + w * 16 + l16) * DH;
#pragma unroll
      for (int ks = 0; ks < 4; ++ks) qf[ks] = *(const short8*)(qrow + ks * 32 + g * 8);
    }
    f32x4 oacc[8];
#pragma unroll
    for (int i = 0; i < 8; ++i) oacc[i] = (f32x4)0.f;
    float m_i[4], l_i[4];
#pragma unroll
    for (int i = 0; i < 4; ++i) { m_i[i] = -INFINITY; l_i[i] = 0.f; }

#pragma unroll
    for (int it = 0; it < 4; ++it) {
      int ci = it * 256 + tid;
      int row = ci >> 4;
      int cb = ((ci & 15) * 16) ^ ((row & 7) << 4);
      async16(Kb + (size_t)row * DH + (cb >> 1), &Ks[0][ci * 8]);
    }
    {
      short8 vr[4];
      vr[0] = *(const short8*)(Vb + (size_t)vkv * DH + vd0);
      vr[1] = *(const short8*)(Vb + (size_t)vkv * DH + vd0 + 8);
      vr[2] = *(const short8*)(Vb + (size_t)(vkv + 1) * DH + vd0);
      vr[3] = *(const short8*)(Vb + (size_t)(vkv + 1) * DH + vd0 + 8);
#pragma unroll
      for (int j = 0; j < 16; ++j) {
        int d = vd0 + j;
        const ushort* a = (const ushort*)&vr[j >> 3];
        const ushort* c = (const ushort*)&vr[2 + (j >> 3)];
        unsigned val = (unsigned)a[j & 7] | ((unsigned)c[j & 7] << 16);
        *(unsigned*)&Vt[0][d * 72 + (vkv ^ vmask)] = val;
      }
    }
    __syncthreads();

    int cur = 0;
    for (int t = 0; t < nkt; ++t) {
      const int k0 = t * 64;
      const int nxt = cur ^ 1;
      const bool pre = (t + 1 < nkt);
      short8 vr[4];
      if (pre) {
        const int kn = (t + 1) * 64;
#pragma unroll
        for (int it = 0; it < 4; ++it) {
          int ci = it * 256 + tid;
          int row = ci >> 4;
          int cb = ((ci & 15) * 16) ^ ((row & 7) << 4);
          async16(Kb + (size_t)(kn + row) * DH + (cb >> 1), &Ks[nxt][ci * 8]);
        }
        vr[0] = *(const short8*)(Vb + (size_t)(kn + vkv) * DH + vd0);
        vr[1] = *(const short8*)(Vb + (size_t)(kn + vkv) * DH + vd0 + 8);
        vr[2] = *(const short8*)(Vb + (size_t)(kn + vkv + 1) * DH + vd0);
        vr[3] = *(const short8*)(Vb + (size_t)(kn + vkv + 1) * DH + vd0 + 8);
      }

      f32x4 sacc[4];
#pragma unroll
      for (int nf = 0; nf < 4; ++nf) sacc[nf] = (f32x4)0.f;
      __builtin_amdgcn_s_setprio(1);
#pragma unroll
      for (int nf = 0; nf < 4; ++nf) {
        int row = nf * 16 + l16;
#pragma unroll
        for (int ks = 0; ks < 4; ++ks) {
          int cb = (ks * 64 + g * 16) ^ ((l16 & 7) << 4);
          short8 kf = *(const short8*)&Ks[cur][row * 128 + (cb >> 1)];
          sacc[nf] = __builtin_amdgcn_mfma_f32_16x16x32_bf16(qf[ks], kf, sacc[nf], 0, 0, 0);
        }
      }
      __builtin_amdgcn_s_setprio(0);

#pragma unroll
      for (int i = 0; i < 4; ++i) {
        int qrow = q0 + w * 16 + g * 4 + i;
        float pv[4];
#pragma unroll
        for (int nf = 0; nf < 4; ++nf) {
          pv[nf] = sacc[nf][i] * scale;
          if (k0 + nf * 16 + l16 > qrow) pv[nf] = -INFINITY;
        }
        float mx = fmaxf(fmaxf(pv[0], pv[1]), fmaxf(pv[2], pv[3]));
#pragma unroll
        for (int d = 1; d < 16; d <<= 1) mx = fmaxf(mx, __shfl_xor(mx, d, 64));
        float mnew = fmaxf(m_i[i], mx);
        float alpha = __expf(m_i[i] - mnew);
        float p[4], sum = 0.f;
#pragma unroll
        for (int nf = 0; nf < 4; ++nf) { p[nf] = __expf(pv[nf] - mnew); sum += p[nf]; }
#pragma unroll
        for (int d = 1; d < 16; d <<= 1) sum += __shfl_xor(sum, d, 64);
        l_i[i] = l_i[i] * alpha + sum;
        m_i[i] = mnew;
#pragma unroll
        for (int nf2 = 0; nf2 < 8; ++nf2) oacc[nf2][i] *= alpha;
#pragma unroll
        for (int nf = 0; nf < 4; ++nf)
          Ps[w][(g * 4 + i) * 72 + nf * 16 + l16] = f2bf(p[nf]);
      }
      __asm__ volatile("s_waitcnt lgkmcnt(0)" ::: "memory");
      __builtin_amdgcn_sched_barrier(0);

      __builtin_amdgcn_s_setprio(1);
#pragma unroll
      for (int kvh = 0; kvh < 2; ++kvh) {
        short8 pa = *(const short8*)&Ps[w][l16 * 72 + kvh * 32 + g * 8];
#pragma unroll
        for (int nf2 = 0; nf2 < 8; ++nf2) {
          int cb = (kvh * 32 + g * 8) ^ (nf2 * 8);
          short8 vf = *(const short8*)&Vt[cur][(nf2 * 16 + l16) * 72 + cb];
          oacc[nf2] = __builtin_amdgcn_mfma_f32_16x16x32_bf16(pa, vf, oacc[nf2], 0, 0, 0);
        }
      }
      __builtin_amdgcn_s_setprio(0);

      if (pre) {
#pragma unroll
        for (int j = 0; j < 16; ++j) {
          int d = vd0 + j;
          const ushort* a = (const ushort*)&vr[j >> 3];
          const ushort* c = (const ushort*)&vr[2 + (j >> 3)];
          unsigned val = (unsigned)a[j & 7] | ((unsigned)c[j & 7] << 16);
          *(unsigned*)&Vt[nxt][d * 72 + (vkv ^ vmask)] = val;
        }
      }
      __syncthreads();
      cur = nxt;
    }

#pragma unroll
    for (int i = 0; i < 4; ++i) {
      float inv = 1.f / l_i[i];
      int row = q0 + w * 16 + g * 4 + i;
      size_t obase = ((size_t)b * SEQ + row) * DMODEL + h * DH;
#pragma unroll
      for (int nf2 = 0; nf2 < 8; ++nf2)
        O[obase + nf2 * 16 + l16] = f2bf(oacc[nf2][i] * inv);
    }
  }
}

// ---------------- launch ----------------
extern "C" void kernel_launch(void* const* d_in, const int* in_sizes, int n_in,
                              void* d_out, int out_size, void* d_ws, size_t ws_size,
                              hipStream_t stream) {
  const float* x    = (const float*)d_in[0];
  const float* wqkv = (const float*)d_in[1];
  const float* wout = (const float*)d_in[2];
  const int*   spp  = (const int*)d_in[3];
  float* out = (float*)d_out;

  ushort* ws = (ushort*)d_ws;
  ushort* xb  = ws;                       // 8,388,608
  ushort* wqb = xb + 8388608;             // 12,582,912
  ushort* wob = wqb + 12582912;           // 4,194,304
  ushort* q   = wob + 4194304;            // 8,388,608
  ushort* k   = q + 8388608;
  ushort* v   = k + 8388608;
  ushort* ao  = v + 8388608;              // 8,388,608

  cast_kernel<<<8388608 / 1024, 256, 0, stream>>>(x, xb, 8388608 / 4);
  cast_kernel<<<12582912 / 1024, 256, 0, stream>>>(wqkv, wqb, 12582912 / 4);
  cast_kernel<<<4194304 / 1024, 256, 0, stream>>>(wout, wob, 4194304 / 4);

  gemm256<0><<<dim3(6144 / 256, 4096 / 256), 512, 0, stream>>>(xb, wqb, 6144, q, k, v, nullptr);

  rope_kernel<<<4194304 / 256, 256, 0, stream>>>(q, k, spp);

  attn_kernel<<<dim3(16, NH, 2), 256, 0, stream>>>(q, k, v, ao);

  gemm256<1><<<dim3(2048 / 256, 4096 / 256), 512, 0, stream>>>(ao, wob, 2048, nullptr, nullptr, nullptr, out);
}